// Round 7
// baseline (204.388 us; speedup 1.0000x reference)
//
#include <hip/hip_runtime.h>

#define LRC   0.01f
#define WCLIP 5.0f
#define LO   (-4.5951198501345898f)
#define HI   ( 4.5951198501345898f)
#define PDSZ (4096 * 256)

__device__ __forceinline__ unsigned short f2bf(float f) {
    unsigned int u = __float_as_uint(f);
    u += 0x7fffu + ((u >> 16) & 1u);          // RNE
    return (unsigned short)(u >> 16);
}
__device__ __forceinline__ float bflo(unsigned int p) { return __uint_as_float(p << 16); }
__device__ __forceinline__ float bfhi(unsigned int p) { return __uint_as_float(p & 0xffff0000u); }

#if defined(__has_builtin)
#if __has_builtin(__builtin_amdgcn_fdot2_f32_bf16)
#define HAVE_DOT2 1
#endif
#endif

#ifdef HAVE_DOT2
typedef __bf16 v2bf __attribute__((ext_vector_type(2)));
__device__ __forceinline__ float dot2(unsigned int w, unsigned int l, float acc) {
    return __builtin_amdgcn_fdot2_f32_bf16(__builtin_bit_cast(v2bf, w),
                                           __builtin_bit_cast(v2bf, l), acc, false);
}
#else
__device__ __forceinline__ float dot2(unsigned int w, unsigned int l, float acc) {
    acc = fmaf(bflo(w), bflo(l), acc);
    return fmaf(bfhi(w), bfhi(l), acc);
}
#endif

// ---------------------------------------------------------------------------
// K1: blocks 0..1023  : distances GEMM 128(m)x64(n) tile, 8x4/thread, BK=32,
//                       K-split 8 (K=64/block) -> 4 blocks/CU = 16 waves/CU.
//     blocks 1024..1087: logits transpose -> lT (fp32) + lp (bf16 i-pairs).
//     blocks 1088..1343: weights fp32 -> wbf bf16 pack (skipped if !wbf).
// ---------------------------------------------------------------------------
__global__ __launch_bounds__(256, 4) void k1_part(
    const float* __restrict__ cmap,    // (4096, 512)
    const float* __restrict__ ctx,     // (512, 256)
    const float* __restrict__ logits,  // (1024, 256)
    const float* __restrict__ weights, // (1024*16, 1024)
    float* __restrict__ pd,            // 8 x (4096, 256) partials (in outw)
    float* __restrict__ lT,            // (256, 1024) fp32
    unsigned int* __restrict__ lp,     // (512, 256) bf16-pairs
    unsigned int* __restrict__ wbf)    // (16384, 512) bf16-pairs, may be null
{
    __shared__ __align__(16) float As[32 * 132];  // As[k][m], stride 132
    __shared__ __align__(16) float Bs[32 * 68];   // Bs[k][n], stride 68
    const int t   = threadIdx.x;
    const int blk = blockIdx.x;

    if (blk < 1024) {
        const int kq = blk & 7;
        const int tN = (blk >> 3) & 3;
        const int tM = blk >> 5;
        const int m0 = tM << 7, n0 = tN << 6, kbase = kq << 6;
        const int tm = t >> 4, tn = t & 15;

        float acc[8][4];
        #pragma unroll
        for (int i = 0; i < 8; i++)
            #pragma unroll
            for (int j = 0; j < 4; j++) acc[i][j] = 0.f;

        // staging: A 4 f4/thread (m=flat>>3, kc=(flat&7)*4); B 2 f4/thread
        float4 va[4], vb[2];
        #pragma unroll
        for (int rep = 0; rep < 4; rep++) {
            int flat = rep * 256 + t;
            va[rep] = *(const float4*)(cmap + (m0 + (flat >> 3)) * 512 + kbase + ((flat & 7) << 2));
        }
        #pragma unroll
        for (int rep = 0; rep < 2; rep++) {
            int flat = rep * 256 + t;
            vb[rep] = *(const float4*)(ctx + (kbase + (flat >> 4)) * 256 + n0 + ((flat & 15) << 2));
        }

        #pragma unroll
        for (int kt = 0; kt < 2; ++kt) {
            __syncthreads();
            #pragma unroll
            for (int rep = 0; rep < 4; rep++) {
                int flat = rep * 256 + t;
                int m = flat >> 3, kc = (flat & 7) << 2;
                As[(kc + 0) * 132 + m] = va[rep].x;
                As[(kc + 1) * 132 + m] = va[rep].y;
                As[(kc + 2) * 132 + m] = va[rep].z;
                As[(kc + 3) * 132 + m] = va[rep].w;
            }
            #pragma unroll
            for (int rep = 0; rep < 2; rep++) {
                int flat = rep * 256 + t;
                *(float4*)(Bs + (flat >> 4) * 68 + ((flat & 15) << 2)) = vb[rep];
            }
            if (kt == 0) {                           // next BK tile in flight
                #pragma unroll
                for (int rep = 0; rep < 4; rep++) {
                    int flat = rep * 256 + t;
                    va[rep] = *(const float4*)(cmap + (m0 + (flat >> 3)) * 512 + kbase + 32 + ((flat & 7) << 2));
                }
                #pragma unroll
                for (int rep = 0; rep < 2; rep++) {
                    int flat = rep * 256 + t;
                    vb[rep] = *(const float4*)(ctx + (kbase + 32 + (flat >> 4)) * 256 + n0 + ((flat & 15) << 2));
                }
            }
            __syncthreads();

            const float* ap = As + (tm << 3);
            const float* bp = Bs + (tn << 2);
            #pragma unroll 4
            for (int k = 0; k < 32; ++k) {
                float4 a0 = *(const float4*)(ap + k * 132);
                float4 a1 = *(const float4*)(ap + k * 132 + 4);
                float4 b4 = *(const float4*)(bp + k * 68);
                const float am[8] = {a0.x, a0.y, a0.z, a0.w, a1.x, a1.y, a1.z, a1.w};
                #pragma unroll
                for (int i = 0; i < 8; i++) {
                    acc[i][0] = fmaf(am[i], b4.x, acc[i][0]);
                    acc[i][1] = fmaf(am[i], b4.y, acc[i][1]);
                    acc[i][2] = fmaf(am[i], b4.z, acc[i][2]);
                    acc[i][3] = fmaf(am[i], b4.w, acc[i][3]);
                }
            }
        }
        float* dst = pd + (long)kq * PDSZ;
        #pragma unroll
        for (int i = 0; i < 8; i++) {
            float4 v = make_float4(acc[i][0], acc[i][1], acc[i][2], acc[i][3]);
            *(float4*)(dst + (m0 + (tm << 3) + i) * 256 + n0 + (tn << 2)) = v;
        }
    } else if (blk < 1088) {
        // transpose one 64(i) x 64(b) tile: -> lT fp32 and lp bf16-pairs
        float* T = As;                                // 64*68 < 32*132 ✓
        const int bi = blk - 1024;
        const int i0 = (bi >> 2) << 6;
        const int b0 = (bi & 3) << 6;
        #pragma unroll
        for (int rep = 0; rep < 4; rep++) {
            int flat4 = rep * 256 + t;
            int r = flat4 >> 4;                       // i-local
            int c = (flat4 & 15) << 2;                // b-local
            float4 v = *(const float4*)(logits + (i0 + r) * 256 + b0 + c);
            T[(c + 0) * 68 + r] = v.x;
            T[(c + 1) * 68 + r] = v.y;
            T[(c + 2) * 68 + r] = v.z;
            T[(c + 3) * 68 + r] = v.w;
        }
        __syncthreads();
        #pragma unroll
        for (int rep = 0; rep < 4; rep++) {
            int flat4 = rep * 256 + t;
            int r = flat4 >> 4;                       // b-local
            int c = (flat4 & 15) << 2;                // i-local
            *(float4*)(lT + (b0 + r) * 1024 + i0 + c) =
                *(const float4*)(T + r * 68 + c);
        }
        #pragma unroll
        for (int rep = 0; rep < 8; rep++) {
            int flat = rep * 256 + t;                 // 0..2047
            int ii = flat >> 6;                       // i2-local 0..31
            int bl = flat & 63;                       // b-local
            float2 v = *(const float2*)(T + bl * 68 + (ii << 1));
            lp[((i0 >> 1) + ii) * 256 + b0 + bl] =
                (unsigned int)f2bf(v.x) | ((unsigned int)f2bf(v.y) << 16);
        }
    } else {
        if (wbf == nullptr) return;
        // pack 64 weight rows (256 KB fp32 -> 128 KB bf16-pairs)
        const int cb = blk - 1088;                    // 0..255
        const float* src = weights + (long)cb * 65536;
        unsigned int* dst = wbf + (long)cb * 32768;
        #pragma unroll 8
        for (int rep = 0; rep < 64; rep++) {
            int flat = rep * 256 + t;
            float4 v = *(const float4*)(src + (flat << 2));
            uint2 o;
            o.x = (unsigned int)f2bf(v.x) | ((unsigned int)f2bf(v.y) << 16);
            o.y = (unsigned int)f2bf(v.z) | ((unsigned int)f2bf(v.w) << 16);
            *(uint2*)(dst + (flat << 1)) = o;
        }
    }
}

// ---------------------------------------------------------------------------
// K2a: idx (8-way pd fold) + forward dots (v_dot2_f32_bf16) + last-b coef.
//      512 blocks x 512 thr: 2 neurons x 256 cols, q = i-half. 4 blocks/CU =
//      32 waves/CU (100% occupancy). Weights bf16-pairs staged in two 512-i
//      chunks (32 KB LDS), XOR-swizzled (j*4 uints -> 2-way max = free);
//      logits read pre-packed from lp. lastb block-local again (no b-split).
// ---------------------------------------------------------------------------
__global__ __launch_bounds__(512, 8) void k2a_fwd(
    const unsigned int* __restrict__ lp,      // (512, 256) bf16-pairs
    const float* __restrict__ targets,  // (256)
    const float* __restrict__ weights,  // fp32, fallback staging
    const unsigned int* __restrict__ wbf, // bf16-pairs, may be null
    const float* __restrict__ bias,     // (1)
    const float* __restrict__ cbias,    // (4096)
    const float* __restrict__ pd,       // 8 x (4096, 256)
    float* __restrict__ outp,           // d_out first 1024*256
    float* __restrict__ coefb,          // (16384) ws
    int*   __restrict__ colb)           // (16384) ws
{
    __shared__ __align__(16) unsigned int wlds[32 * 256];  // 32 KB bf16-pairs
    __shared__ int   idx_lds[512];            // [g][256]
    __shared__ float red[512];                // [g][256] (q=1 partials)
    __shared__ float sig_lds[512];            // [g][256]
    __shared__ int   lastb[32];

    const int t   = threadIdx.x;
    const int col = t & 255;
    const int q   = t >> 8;               // i-half
    const int s0  = blockIdx.x << 1;      // 2 neurons

    if (t < 32) lastb[t] = -1;

    // ---- staging geometry: row r = t>>4 (32 rows), 16 thr/row ----
    const int r    = t >> 4;
    const int lane = t & 15;
    const long rowG = ((long)(s0 + (r >> 4)) << 4) + (r & 15);   // global row
    const int  jr   = r & 15;
    const int  swzr = jr << 2;            // staging swizzle (uints)

    // ---- chunk 0 staging loads (in flight during idx fold) ----
    uint4 pf[4];
    if (wbf) {
        const unsigned int* wsrc = wbf + rowG * 512 + (lane << 4);
        #pragma unroll
        for (int seg = 0; seg < 4; ++seg)
            pf[seg] = *(const uint4*)(wsrc + (seg << 2));
    } else {
        const float* wsrc = weights + rowG * 1024 + (lane << 5);
        #pragma unroll
        for (int seg = 0; seg < 4; ++seg) {
            float4 v0 = *(const float4*)(wsrc + (seg << 3));
            float4 v1 = *(const float4*)(wsrc + (seg << 3) + 4);
            pf[seg].x = (unsigned int)f2bf(v0.x) | ((unsigned int)f2bf(v0.y) << 16);
            pf[seg].y = (unsigned int)f2bf(v0.z) | ((unsigned int)f2bf(v0.w) << 16);
            pf[seg].z = (unsigned int)f2bf(v1.x) | ((unsigned int)f2bf(v1.y) << 16);
            pf[seg].w = (unsigned int)f2bf(v1.z) | ((unsigned int)f2bf(v1.w) << 16);
        }
    }

    // ---- idx: thread computes neuron s0+q, column col (8-way pd fold) ----
    {
        int v = 0;
        #pragma unroll
        for (int mm = 0; mm < 4; mm++) {
            const float* pp = pd + ((s0 + q) * 4 + mm) * 256 + col;
            float d = ((pp[0] + pp[PDSZ]) + (pp[2 * PDSZ] + pp[3 * PDSZ]))
                    + ((pp[4 * PDSZ] + pp[5 * PDSZ]) + (pp[6 * PDSZ] + pp[7 * PDSZ]));
            v |= (d > cbias[(s0 + q) * 4 + mm]) ? (1 << mm) : 0;
        }
        idx_lds[(q << 8) + col] = v;
    }

    // ---- write chunk 0 to LDS (XOR swizzle) ----
    {
        unsigned int* ldst = wlds + (r << 8);
        const int ob = lane << 4;
        #pragma unroll
        for (int seg = 0; seg < 4; ++seg)
            *(uint4*)(ldst + ((ob + (seg << 2)) ^ swzr)) = pf[seg];
    }
    __syncthreads();      // lastb init, idx_lds, wlds chunk 0 all visible

    // last-b argmax (LDS-local; both q halves cover both neurons via q=own g)
    atomicMax(&lastb[(q << 4) + idx_lds[(q << 8) + col]], col);

    int rowoff[2], gswz[2];
    #pragma unroll
    for (int g = 0; g < 2; g++) {
        int v = idx_lds[(g << 8) + col];
        rowoff[g] = ((g << 4) + v) << 8;  // row * 256 uints
        gswz[g]   = v << 2;
    }

    // ---- prefetch chunk 1 (HBM overlaps chunk-0 compute) ----
    if (wbf) {
        const unsigned int* wsrc = wbf + rowG * 512 + 256 + (lane << 4);
        #pragma unroll
        for (int seg = 0; seg < 4; ++seg)
            pf[seg] = *(const uint4*)(wsrc + (seg << 2));
    } else {
        const float* wsrc = weights + rowG * 1024 + 512 + (lane << 5);
        #pragma unroll
        for (int seg = 0; seg < 4; ++seg) {
            float4 v0 = *(const float4*)(wsrc + (seg << 3));
            float4 v1 = *(const float4*)(wsrc + (seg << 3) + 4);
            pf[seg].x = (unsigned int)f2bf(v0.x) | ((unsigned int)f2bf(v0.y) << 16);
            pf[seg].y = (unsigned int)f2bf(v0.z) | ((unsigned int)f2bf(v0.w) << 16);
            pf[seg].z = (unsigned int)f2bf(v1.x) | ((unsigned int)f2bf(v1.y) << 16);
            pf[seg].w = (unsigned int)f2bf(v1.z) | ((unsigned int)f2bf(v1.w) << 16);
        }
    }

    float acc[2] = {0.f, 0.f};
    const int qu = q << 7;                // q-half base, uints within chunk

    // ---- compute chunk 0 (i 0..511) ----
    #pragma unroll 4
    for (int uu = 0; uu < 128; uu += 4) {
        const int u0 = qu + uu;           // chunk-local uint index (4-aligned)
        unsigned int l0 = lp[(u0 + 0) * 256 + col];
        unsigned int l1 = lp[(u0 + 1) * 256 + col];
        unsigned int l2 = lp[(u0 + 2) * 256 + col];
        unsigned int l3 = lp[(u0 + 3) * 256 + col];
        #pragma unroll
        for (int g = 0; g < 2; g++) {
            uint4 wp = *(const uint4*)(wlds + rowoff[g] + (u0 ^ gswz[g]));
            acc[g] = dot2(wp.x, l0, acc[g]);
            acc[g] = dot2(wp.y, l1, acc[g]);
            acc[g] = dot2(wp.z, l2, acc[g]);
            acc[g] = dot2(wp.w, l3, acc[g]);
        }
    }
    __syncthreads();

    // ---- write chunk 1 ----
    {
        unsigned int* ldst = wlds + (r << 8);
        const int ob = lane << 4;
        #pragma unroll
        for (int seg = 0; seg < 4; ++seg)
            *(uint4*)(ldst + ((ob + (seg << 2)) ^ swzr)) = pf[seg];
    }
    __syncthreads();

    // ---- compute chunk 1 (i 512..1023) ----
    #pragma unroll 4
    for (int uu = 0; uu < 128; uu += 4) {
        const int u0 = qu + uu;
        unsigned int l0 = lp[(256 + u0 + 0) * 256 + col];
        unsigned int l1 = lp[(256 + u0 + 1) * 256 + col];
        unsigned int l2 = lp[(256 + u0 + 2) * 256 + col];
        unsigned int l3 = lp[(256 + u0 + 3) * 256 + col];
        #pragma unroll
        for (int g = 0; g < 2; g++) {
            uint4 wp = *(const uint4*)(wlds + rowoff[g] + (u0 ^ gswz[g]));
            acc[g] = dot2(wp.x, l0, acc[g]);
            acc[g] = dot2(wp.y, l1, acc[g]);
            acc[g] = dot2(wp.z, l2, acc[g]);
            acc[g] = dot2(wp.w, l3, acc[g]);
        }
    }
    __syncthreads();

    // ---- reduce halves, clip, bias, sigmoid ----
    if (q == 1) {
        red[col]       = acc[0];
        red[256 + col] = acc[1];
    }
    __syncthreads();
    if (q == 0) {
        #pragma unroll
        for (int g = 0; g < 2; g++) {
            float tot  = acc[g] + red[(g << 8) + col];
            float outv = fminf(fmaxf(tot, LO), HI);
            if (s0 + g == 0) outv = bias[0];      // neuron 0 forced to bias
            outp[(s0 + g) * 256 + col] = outv;
            sig_lds[(g << 8) + col] = 1.f / (1.f + __expf(-outv));
        }
    }
    __syncthreads();
    if (t < 32) {
        int g  = t >> 4;
        int bb = lastb[t];
        float cfv = 0.f;
        if (bb >= 0) cfv = LRC * (sig_lds[(g << 8) + bb] - targets[bb]);
        coefb[(s0 << 4) + t] = cfv;
        colb [(s0 << 4) + t] = bb;
    }
}

// ---------------------------------------------------------------------------
// K2b: streaming update  new_w = clamp(w - coef*lT[b*], +-5)  (or copy).
//      Reads wbf (exact bf16 of 1/1024) when available: -32 MB HBM.
// ---------------------------------------------------------------------------
__global__ __launch_bounds__(256) void k2b_update(
    const float* __restrict__ weights,
    const unsigned int* __restrict__ wbf,   // may be null
    const float* __restrict__ lT,
    const float* __restrict__ coefb,
    const int*   __restrict__ colb,
    float* __restrict__ outw)
{
    const int t  = threadIdx.x;
    const int r0 = blockIdx.x << 2;
    const int o  = t << 2;
    #pragma unroll
    for (int rr = 0; rr < 4; rr++) {
        const int row = r0 + rr;
        const int col = colb[row];        // uniform across block
        const float cf = coefb[row];
        float4 wv;
        if (wbf) {
            uint2 u = *(const uint2*)(wbf + (long)row * 512 + (t << 1));
            wv.x = bflo(u.x); wv.y = bfhi(u.x);
            wv.z = bflo(u.y); wv.w = bfhi(u.y);
        } else {
            wv = *(const float4*)(weights + (long)row * 1024 + o);
        }
        float4 res = wv;                  // untouched row: verbatim copy
        if (col >= 0) {
            float4 lv = *(const float4*)(lT + (long)col * 1024 + o);
            res.x = fminf(fmaxf(wv.x - cf * lv.x, -WCLIP), WCLIP);
            res.y = fminf(fmaxf(wv.y - cf * lv.y, -WCLIP), WCLIP);
            res.z = fminf(fmaxf(wv.z - cf * lv.z, -WCLIP), WCLIP);
            res.w = fminf(fmaxf(wv.w - cf * lv.w, -WCLIP), WCLIP);
        }
        *(float4*)(outw + (long)row * 1024 + o) = res;
    }
}

// ---------------------------------------------------------------------------
extern "C" void kernel_launch(void* const* d_in, const int* in_sizes, int n_in,
                              void* d_out, int out_size, void* d_ws, size_t ws_size,
                              hipStream_t stream) {
    const float* logits  = (const float*)d_in[0];   // (1024, 256)
    const float* ctx     = (const float*)d_in[1];   // (512, 256)
    const float* targets = (const float*)d_in[2];   // (256)
    const float* weights = (const float*)d_in[3];   // (1024, 16, 1024)
    const float* cmap    = (const float*)d_in[4];   // (1024, 4, 512)
    const float* cbias   = (const float*)d_in[5];   // (1024, 4, 1)
    const float* bias    = (const float*)d_in[6];   // (1)

    float* outp = (float*)d_out;                    // (1024, 256)
    float* outw = outp + 1024 * 256;                // (1024, 16, 1024)

    char* ws = (char*)d_ws;
    float*        lT    = (float*)ws;                        // 1 MB
    unsigned int* lp    = (unsigned int*)(ws + (1 << 20));   // 512 KB
    float*        coefb = (float*)(ws + 1536 * 1024);        // 64 KB
    int*          colb  = (int*)  (ws + 1536 * 1024 + (1 << 16));
    unsigned int* wbf   = nullptr;                           // 32 MB @ 2 MB
    if (ws_size >= (size_t)(2 << 20) + (32u << 20))
        wbf = (unsigned int*)(ws + (2 << 20));

    // K1 partials: 8 x 4 MB = 32 MB carved from outw (dead until k2b writes).
    float* pd = outw;

    k1_part   <<<1344, 256, 0, stream>>>(cmap, ctx, logits, weights,
                                         pd, lT, lp, wbf);
    k2a_fwd   <<<512, 512, 0, stream>>>(lp, targets, weights, wbf, bias,
                                        cbias, pd, outp, coefb, colb);
    k2b_update<<<4096, 256, 0, stream>>>(weights, wbf, lT, coefb, colb, outw);
}